// Round 5
// baseline (417.120 us; speedup 1.0000x reference)
//
#include <hip/hip_runtime.h>
#include <hip/hip_bf16.h>
#include <math.h>

#define Hdim 128
#define NBq 8
#define SIq 16

// ---------------- gather: X0 = embedding[node_ids] ----------------
__global__ void k_gather(const float* __restrict__ emb, const int* __restrict__ ids,
                         float* __restrict__ x0, int N) {
  int idx = blockIdx.x * blockDim.x + threadIdx.x;
  int total = N * (Hdim / 4);
  if (idx >= total) return;
  int n  = idx / (Hdim / 4);
  int c4 = idx - n * (Hdim / 4);
  int s  = ids[n];
  ((float4*)x0)[(size_t)n * (Hdim / 4) + c4] =
      ((const float4*)emb)[(size_t)s * (Hdim / 4) + c4];
}

// ---------------- dst CSR: histogram / scan / position assign ----------------
__global__ void k_hist(const int* __restrict__ dst, int* __restrict__ cnt, int E) {
  int e = blockIdx.x * blockDim.x + threadIdx.x;
  if (e < E) atomicAdd(&cnt[dst[e]], 1);
}

__global__ __launch_bounds__(1024) void k_scan(const int* __restrict__ cnt,
                                               int* __restrict__ off,
                                               int* __restrict__ cur, int N, int E) {
  __shared__ int part[1024];
  int t = threadIdx.x;
  int ipt = N / 1024;
  int base = t * ipt;
  int loc[8];
  int s = 0;
  for (int i = 0; i < ipt; ++i) { loc[i] = s; s += cnt[base + i]; }
  part[t] = s;
  __syncthreads();
  for (int d = 1; d < 1024; d <<= 1) {
    int v = part[t];
    int add = (t >= d) ? part[t - d] : 0;
    __syncthreads();
    part[t] = v + add;
    __syncthreads();
  }
  int pre = (t == 0) ? 0 : part[t - 1];
  for (int i = 0; i < ipt; ++i) {
    int o = pre + loc[i];
    off[base + i] = o;
    cur[base + i] = o;
  }
  if (t == 0) off[N] = E;
}

__global__ void k_posd(const int* __restrict__ dst, int* __restrict__ cur,
                       int* __restrict__ pos, int E) {
  int e = blockIdx.x * blockDim.x + threadIdx.x;
  if (e < E) pos[e] = atomicAdd(&cur[dst[e]], 1);
}

// ---------------- etype sort (block-local LDS ranking -> low contention) ----------------
__global__ __launch_bounds__(256) void k_hist_et(const int* __restrict__ et,
                                                 int* __restrict__ cnt, int E, int NR) {
  __shared__ int lc[128];
  int t = threadIdx.x;
  if (t < NR) lc[t] = 0;
  __syncthreads();
  int e = blockIdx.x * 256 + t;
  if (e < E) atomicAdd(&lc[et[e]], 1);
  __syncthreads();
  if (t < NR && lc[t]) atomicAdd(&cnt[t], lc[t]);
}

__global__ void k_scan_et(const int* __restrict__ cnt, int* __restrict__ cur, int NR) {
  if (threadIdx.x == 0 && blockIdx.x == 0) {
    int s = 0;
    for (int i = 0; i < NR; ++i) { cur[i] = s; s += cnt[i]; }
  }
}

__global__ __launch_bounds__(256) void k_scat_et(
    const int* __restrict__ src, const int* __restrict__ et,
    const float* __restrict__ norm, const int* __restrict__ pos_dst,
    int* __restrict__ cur_et,
    int* __restrict__ src_et, int* __restrict__ r_et,
    int* __restrict__ op_et, float* __restrict__ nrm_et, int E, int NR) {
  __shared__ int lc[128], lbase[128];
  int t = threadIdx.x;
  if (t < NR) lc[t] = 0;
  __syncthreads();
  int e = blockIdx.x * 256 + t;
  int r = 0, lr = 0;
  bool ok = e < E;
  if (ok) { r = et[e]; lr = atomicAdd(&lc[r], 1); }
  __syncthreads();
  if (t < NR && lc[t]) lbase[t] = atomicAdd(&cur_et[t], lc[t]);
  __syncthreads();
  if (ok) {
    int s = lbase[r] + lr;
    src_et[s] = src[e];
    r_et[s]  = r;
    op_et[s] = pos_dst[e];
    nrm_et[s] = norm[e];
  }
}

// ---------------- phase 1: relation-major message compute ----------------
// W fragment (16 floats) in registers, reloaded only on (uniform) relation
// change. x rows direct from global (h is 4 MB -> L2-resident; 16 lanes per
// b-group broadcast the same 16B). msg written at dst-sorted slot, 512B rows.
#define MCHUNK 32
__global__ __launch_bounds__(128) void k_msg(
    const float* __restrict__ h, const float* __restrict__ W,
    const int* __restrict__ src_et, const int* __restrict__ r_et,
    const int* __restrict__ op_et, const float* __restrict__ nrm_et,
    float* __restrict__ msg, int E) {
  int f = threadIdx.x, b = f >> 4, o = f & 15;
  int j0 = blockIdx.x * MCHUNK;
  int j1 = min(j0 + MCHUNK, E);
  float w[16];
  int cur = -1;
  for (int j = j0; j < j1; ++j) {
    int r = r_et[j];
    if (r != cur) {           // wave-uniform branch (etype-sorted)
      cur = r;
      const float* wp = W + ((size_t)r * NBq + b) * (SIq * SIq) + o;
#pragma unroll
      for (int i = 0; i < SIq; ++i) w[i] = wp[i * SIq];   // 4x64B segs/wave/step
    }
    int s = src_et[j];
    const float4* xp = (const float4*)(h + (size_t)s * Hdim + b * SIq);
    float4 x0 = xp[0], x1 = xp[1], x2 = xp[2], x3 = xp[3];
    float a = x0.x*w[0]  + x0.y*w[1]  + x0.z*w[2]  + x0.w*w[3]
            + x1.x*w[4]  + x1.y*w[5]  + x1.z*w[6]  + x1.w*w[7]
            + x2.x*w[8]  + x2.y*w[9]  + x2.z*w[10] + x2.w*w[11]
            + x3.x*w[12] + x3.y*w[13] + x3.z*w[14] + x3.w*w[15];
    msg[(size_t)op_et[j] * Hdim + f] = a * nrm_et[j];
  }
}

// ---------------- phase 2: segment-sum of dst-sorted msg rows ----------------
__global__ __launch_bounds__(128) void k_red(
    const float* __restrict__ msg, const int* __restrict__ off,
    float* __restrict__ agg) {
  int n = blockIdx.x, f = threadIdx.x;
  int j0 = off[n], j1 = off[n + 1];
  float a = 0.f;
  for (int j = j0; j < j1; ++j) a += msg[(size_t)j * Hdim + f];
  agg[(size_t)n * Hdim + f] = a;
}

// ---------------- GEMM: C[M,Nc] = A[M,128] @ B[128,Nc] (+addm)(+bias)(+addm2)(relu) ----------------
__global__ __launch_bounds__(256) void k_gemm(
    const float* __restrict__ A, const float* __restrict__ B, float* __restrict__ C,
    const float* __restrict__ addm, const float* __restrict__ bias,
    const float* __restrict__ addm2, int M, int Nc, int relu) {
  __shared__ float As[32][34];
  __shared__ float Bs[32][64];
  int t  = threadIdx.x;
  int tx = t & 15, ty = t >> 4;
  int bm = blockIdx.x * 32, bn = blockIdx.y * 64;
  int arow = t >> 3, akq = (t & 7) << 2;
  int br0 = t >> 4,         bc0 = (t & 15) << 2;
  int br1 = (t + 256) >> 4, bc1 = bc0;
  float acc[2][4] = {};
  for (int k0 = 0; k0 < Hdim; k0 += 32) {
    float4 av  = *(const float4*)(A + (size_t)(bm + arow) * Hdim + k0 + akq);
    float4 bv0 = *(const float4*)(B + (size_t)(k0 + br0) * Nc + bn + bc0);
    float4 bv1 = *(const float4*)(B + (size_t)(k0 + br1) * Nc + bn + bc1);
    __syncthreads();
    As[akq + 0][arow] = av.x; As[akq + 1][arow] = av.y;
    As[akq + 2][arow] = av.z; As[akq + 3][arow] = av.w;
    *(float4*)&Bs[br0][bc0] = bv0;
    *(float4*)&Bs[br1][bc1] = bv1;
    __syncthreads();
#pragma unroll
    for (int kk = 0; kk < 32; ++kk) {
      float2 a  = *(const float2*)&As[kk][ty << 1];
      float4 bb = *(const float4*)&Bs[kk][tx << 2];
      acc[0][0] += a.x * bb.x; acc[0][1] += a.x * bb.y;
      acc[0][2] += a.x * bb.z; acc[0][3] += a.x * bb.w;
      acc[1][0] += a.y * bb.x; acc[1][1] += a.y * bb.y;
      acc[1][2] += a.y * bb.z; acc[1][3] += a.y * bb.w;
    }
  }
  int col = bn + (tx << 2);
  float4 bvv = {0.f, 0.f, 0.f, 0.f};
  if (bias) bvv = *(const float4*)(bias + col);
#pragma unroll
  for (int r = 0; r < 2; ++r) {
    int row = bm + (ty << 1) + r;
    size_t off = (size_t)row * Nc + col;
    float4 v;
    v.x = acc[r][0] + bvv.x; v.y = acc[r][1] + bvv.y;
    v.z = acc[r][2] + bvv.z; v.w = acc[r][3] + bvv.w;
    if (addm)  { float4 m = *(const float4*)(addm + off);  v.x += m.x; v.y += m.y; v.z += m.z; v.w += m.w; }
    if (addm2) { float4 m = *(const float4*)(addm2 + off); v.x += m.x; v.y += m.y; v.z += m.z; v.w += m.w; }
    if (relu) {
      v.x = fmaxf(v.x, 0.f); v.y = fmaxf(v.y, 0.f);
      v.z = fmaxf(v.z, 0.f); v.w = fmaxf(v.w, 0.f);
    }
    *(float4*)(C + off) = v;
  }
}

// ---------------- z = zml[:, :128] + exp(zml[:, 128:]) * eps ----------------
__global__ void k_z(const float* __restrict__ zml, const float* __restrict__ eps,
                    float* __restrict__ z, int N) {
  int idx = blockIdx.x * blockDim.x + threadIdx.x;
  if (idx >= N * Hdim) return;
  int n = idx >> 7, j = idx & 127;
  float mean = zml[(size_t)n * 256 + j];
  float ls   = zml[(size_t)n * 256 + 128 + j];
  z[idx] = mean + expf(ls) * eps[idx];
}

// ---------------- G[128,128] += X^T @ Y  (split-K, 4x4/thread, no spill) ----------------
__global__ __launch_bounds__(256) void k_xty(const float* __restrict__ X,
                                             const float* __restrict__ Y,
                                             float* __restrict__ G, int N) {
  __shared__ float xs[8][64];
  __shared__ float ys[8][64];
  int t  = threadIdx.x;
  int tx = t & 15, ty = t >> 4;
  int qr = blockIdx.y >> 1, qc = blockIdx.y & 1;
  int KC = N / gridDim.x;
  int k0 = blockIdx.x * KC;
  int m  = t >> 7, li = t & 127;
  int lr = li >> 4, lc = (li & 15) << 2;
  const float* S = m ? Y : X;
  int coff = (m ? qc : qr) * 64;
  float acc[4][4] = {};
  for (int kb = 0; kb < KC; kb += 8) {
    float4 v = *(const float4*)(S + (size_t)(k0 + kb + lr) * Hdim + coff + lc);
    __syncthreads();
    if (m) *(float4*)&ys[lr][lc] = v; else *(float4*)&xs[lr][lc] = v;
    __syncthreads();
#pragma unroll
    for (int kk = 0; kk < 8; ++kk) {
      float4 xv = *(const float4*)&xs[kk][ty << 2];
      float4 yv = *(const float4*)&ys[kk][tx << 2];
      acc[0][0] += xv.x * yv.x; acc[0][1] += xv.x * yv.y; acc[0][2] += xv.x * yv.z; acc[0][3] += xv.x * yv.w;
      acc[1][0] += xv.y * yv.x; acc[1][1] += xv.y * yv.y; acc[1][2] += xv.y * yv.z; acc[1][3] += xv.y * yv.w;
      acc[2][0] += xv.z * yv.x; acc[2][1] += xv.z * yv.y; acc[2][2] += xv.z * yv.z; acc[2][3] += xv.z * yv.w;
      acc[3][0] += xv.w * yv.x; acc[3][1] += xv.w * yv.y; acc[3][2] += xv.w * yv.z; acc[3][3] += xv.w * yv.w;
    }
  }
  int grow = qr * 64 + (ty << 2);
  int gcol = qc * 64 + (tx << 2);
#pragma unroll
  for (int r = 0; r < 4; ++r)
#pragma unroll
    for (int c = 0; c < 4; ++c)
      atomicAdd(&G[(size_t)(grow + r) * Hdim + gcol + c], acc[r][c]);
}

extern "C" void kernel_launch(void* const* d_in, const int* in_sizes, int n_in,
                              void* d_out, int out_size, void* d_ws, size_t ws_size,
                              hipStream_t stream) {
  const int*   node_ids = (const int*)d_in[0];
  const int*   src      = (const int*)d_in[1];
  const int*   dst      = (const int*)d_in[2];
  const int*   et       = (const int*)d_in[3];
  const float* norm     = (const float*)d_in[4];
  const float* eps      = (const float*)d_in[5];
  const float* emb      = (const float*)d_in[6];
  const float* W0       = (const float*)d_in[7];
  const float* loop0    = (const float*)d_in[8];
  const float* b0       = (const float*)d_in[9];
  const float* W1       = (const float*)d_in[10];
  const float* loop1    = (const float*)d_in[11];
  const float* b1       = (const float*)d_in[12];
  const float* Wz       = (const float*)d_in[13];
  const float* bz       = (const float*)d_in[14];
  const float* Wi       = (const float*)d_in[15];
  const float* bi       = (const float*)d_in[16];
  const float* hbi      = (const float*)d_in[17];
  const float* Wo       = (const float*)d_in[18];
  const float* bo       = (const float*)d_in[19];
  const float* hbo      = (const float*)d_in[20];
  float* out = (float*)d_out;

  const int N  = in_sizes[0];   // 8192
  const int E  = in_sizes[1];   // 131072
  const int NR = in_sizes[7] / (NBq * SIq * SIq);   // 90 relations

  char* ws = (char*)d_ws;
  const size_t MB = 1u << 20;
  const size_t KB = 1u << 10;
  float* X0   = (float*)(ws + 0 * MB);
  float* B1p  = (float*)(ws + 4 * MB);
  float* B2p  = (float*)(ws + 8 * MB);
  float* AGG  = (float*)(ws + 12 * MB);
  float* B3p  = (float*)(ws + 16 * MB);
  float* ZML  = (float*)(ws + 12 * MB);   // overlaps AGG+B3p (both dead then)
  float* G    = (float*)(ws + 20 * MB);
  int*   offp = (int*)(ws + 20 * MB + 256 * KB);
  int*   curp = (int*)(ws + 20 * MB + 512 * KB);
  int*   cntp = (int*)(ws + 20 * MB + 768 * KB);
  int*   etcnt = (int*)(ws + 20 * MB + 832 * KB);
  int*   etcur = (int*)(ws + 20 * MB + 840 * KB);
  int*   posd  = (int*)(ws + 21 * MB);             // E ints (512 KB)
  int*   src_et = (int*)(ws + 21 * MB + 512 * KB);
  int*   r_et   = (int*)(ws + 22 * MB);
  int*   op_et  = (int*)(ws + 22 * MB + 512 * KB);
  float* nrm_et = (float*)(ws + 23 * MB);
  float* MSG    = (float*)(ws + 24 * MB);          // E*128 fp32 = 67 MB (needs ws >= 96 MB)

  dim3 blk(256);

  // ---- preprocessing: dst CSR + etype sort (amortized over both layers) ----
  hipMemsetAsync(cntp, 0, (size_t)N * sizeof(int), stream);
  hipMemsetAsync(etcnt, 0, 128 * sizeof(int), stream);
  k_hist<<<dim3((E + 255) / 256), blk, 0, stream>>>(dst, cntp, E);
  k_scan<<<dim3(1), dim3(1024), 0, stream>>>(cntp, offp, curp, N, E);
  k_posd<<<dim3((E + 255) / 256), blk, 0, stream>>>(dst, curp, posd, E);
  k_hist_et<<<dim3((E + 255) / 256), blk, 0, stream>>>(et, etcnt, E, NR);
  k_scan_et<<<dim3(1), dim3(64), 0, stream>>>(etcnt, etcur, NR);
  k_scat_et<<<dim3((E + 255) / 256), blk, 0, stream>>>(src, et, norm, posd, etcur,
                                                       src_et, r_et, op_et, nrm_et, E, NR);

  // 1. x0
  k_gather<<<dim3((N * (Hdim / 4) + 255) / 256), blk, 0, stream>>>(emb, node_ids, X0, N);
  // 2. layer-0 edges: relation-major msg, then dst segment-sum
  k_msg<<<dim3((E + MCHUNK - 1) / MCHUNK), dim3(128), 0, stream>>>(X0, W0, src_et, r_et, op_et, nrm_et, MSG, E);
  k_red<<<dim3(N), dim3(128), 0, stream>>>(MSG, offp, AGG);
  // 3. h1 = relu(agg + b0 + x0@loop0)
  k_gemm<<<dim3(N / 32, Hdim / 64), blk, 0, stream>>>(X0, loop0, B1p, AGG, b0, nullptr, N, Hdim, 1);
  // 4. layer-1 edges
  k_msg<<<dim3((E + MCHUNK - 1) / MCHUNK), dim3(128), 0, stream>>>(B1p, W1, src_et, r_et, op_et, nrm_et, MSG, E);
  k_red<<<dim3(N), dim3(128), 0, stream>>>(MSG, offp, AGG);
  // 5. h2 = agg + b1 + h1@loop1
  k_gemm<<<dim3(N / 32, Hdim / 64), blk, 0, stream>>>(B1p, loop1, B2p, AGG, b1, nullptr, N, Hdim, 0);
  // 6. zml = h2@Wz + bz   [N, 256]
  k_gemm<<<dim3(N / 32, 256 / 64), blk, 0, stream>>>(B2p, Wz, ZML, nullptr, bz, nullptr, N, 256, 0);
  // 7. z = mean + exp(log_std)*eps  -> B1p
  k_z<<<dim3((N * Hdim) / 256), blk, 0, stream>>>(ZML, eps, B1p, N);
  // 8. C1 = z@Wi + bi + x0 -> B3p
  k_gemm<<<dim3(N / 32, Hdim / 64), blk, 0, stream>>>(B1p, Wi, B3p, nullptr, bi, X0, N, Hdim, 0);
  // 9. G1 = z^T @ C1
  hipMemsetAsync(G, 0, (size_t)Hdim * Hdim * sizeof(float), stream);
  k_xty<<<dim3(32, 4), blk, 0, stream>>>(B1p, B3p, G, N);
  // 10. h3 = z@G1 + hbi -> B2p
  k_gemm<<<dim3(N / 32, Hdim / 64), blk, 0, stream>>>(B1p, G, B2p, nullptr, hbi, nullptr, N, Hdim, 0);
  // 11. C2 = h3@Wo + bo + x0 -> B3p
  k_gemm<<<dim3(N / 32, Hdim / 64), blk, 0, stream>>>(B2p, Wo, B3p, nullptr, bo, X0, N, Hdim, 0);
  // 12. G2 = h3^T @ C2
  hipMemsetAsync(G, 0, (size_t)Hdim * Hdim * sizeof(float), stream);
  k_xty<<<dim3(32, 4), blk, 0, stream>>>(B2p, B3p, G, N);
  // 13. out = h3@G2 + hbo
  k_gemm<<<dim3(N / 32, Hdim / 64), blk, 0, stream>>>(B2p, G, out, nullptr, hbo, nullptr, N, Hdim, 0);
}

// Round 6
// 327.029 us; speedup vs baseline: 1.2755x; 1.2755x over previous
//
#include <hip/hip_runtime.h>
#include <hip/hip_bf16.h>
#include <math.h>

#define Hdim 128
#define NBq 8
#define SIq 16

// ---------------- gather: X0 = embedding[node_ids] ----------------
__global__ void k_gather(const float* __restrict__ emb, const int* __restrict__ ids,
                         float* __restrict__ x0, int N) {
  int idx = blockIdx.x * blockDim.x + threadIdx.x;
  int total = N * (Hdim / 4);
  if (idx >= total) return;
  int n  = idx / (Hdim / 4);
  int c4 = idx - n * (Hdim / 4);
  int s  = ids[n];
  ((float4*)x0)[(size_t)n * (Hdim / 4) + c4] =
      ((const float4*)emb)[(size_t)s * (Hdim / 4) + c4];
}

// ---------------- W -> bf16, transposed: Wt[rb][o][i] = bf16(W[rb][i][o]) ----------------
__global__ void k_wtb(const float* __restrict__ W, unsigned short* __restrict__ Wt) {
  int rb = blockIdx.x;
  int t  = threadIdx.x;          // 256
  int i = t >> 4, o = t & 15;
  unsigned int u = __float_as_uint(W[(size_t)rb * 256 + i * 16 + o]);
  unsigned int r = (u + 0x7fffu + ((u >> 16) & 1u)) >> 16;   // RNE
  Wt[(size_t)rb * 256 + o * 16 + i] = (unsigned short)r;
}

// ---------------- dst CSR: histogram / scan / scatter-permute ----------------
__global__ void k_hist(const int* __restrict__ dst, int* __restrict__ cnt, int E) {
  int e = blockIdx.x * blockDim.x + threadIdx.x;
  if (e < E) atomicAdd(&cnt[dst[e]], 1);
}

__global__ __launch_bounds__(1024) void k_scan(const int* __restrict__ cnt,
                                               int* __restrict__ off,
                                               int* __restrict__ cur, int N, int E) {
  __shared__ int part[1024];
  int t = threadIdx.x;
  int ipt = N / 1024;
  int base = t * ipt;
  int loc[8];
  int s = 0;
  for (int i = 0; i < ipt; ++i) { loc[i] = s; s += cnt[base + i]; }
  part[t] = s;
  __syncthreads();
  for (int d = 1; d < 1024; d <<= 1) {
    int v = part[t];
    int add = (t >= d) ? part[t - d] : 0;
    __syncthreads();
    part[t] = v + add;
    __syncthreads();
  }
  int pre = (t == 0) ? 0 : part[t - 1];
  for (int i = 0; i < ipt; ++i) {
    int o = pre + loc[i];
    off[base + i] = o;
    cur[base + i] = o;
  }
  if (t == 0) off[N] = E;
}

__global__ void k_scatter(const int* __restrict__ src, const int* __restrict__ dst,
                          const int* __restrict__ et, const float* __restrict__ norm,
                          int* __restrict__ cur, int* __restrict__ psrc,
                          int* __restrict__ pet, float* __restrict__ pnorm, int E) {
  int e = blockIdx.x * blockDim.x + threadIdx.x;
  if (e >= E) return;
  int p = atomicAdd(&cur[dst[e]], 1);
  psrc[p] = src[e];
  pet[p]  = et[e];
  pnorm[p] = norm[e];
}

// ---------------- segment-reduce edge aggregation, bf16 W ----------------
// one block (128 threads) per dst node; 8 edges per sync round.
// W per edge: 2x uint4 (16B) loads/thread of bf16, lanes o=0..15 at 32B
// stride -> full 64B-line utilization, 4 KB L2 traffic/edge (vs 8 KB fp32).
#define BF_LO(u) __uint_as_float((u) << 16)
#define BF_HI(u) __uint_as_float((u) & 0xffff0000u)
__global__ __launch_bounds__(128) void k_edge4(
    const float* __restrict__ h, const unsigned short* __restrict__ Wt,
    const int* __restrict__ off, const int* __restrict__ psrc,
    const int* __restrict__ pet, const float* __restrict__ pnorm,
    float* __restrict__ agg) {
  int n = blockIdx.x;
  int f = threadIdx.x;          // feature 0..127
  int b = f >> 4, o = f & 15;
  int j0 = off[n], j1 = off[n + 1];
  __shared__ float xs[8][Hdim];
  float acc = 0.f;
  for (int j = j0; j < j1; j += 8) {
    int m = min(8, j1 - j);
    for (int q = 0; q < m; ++q)
      xs[q][f] = h[(size_t)psrc[j + q] * Hdim + f];
    __syncthreads();
    for (int q = 0; q < m; ++q) {
      int r = pet[j + q];
      float nv = pnorm[j + q];
      const uint4* wp = (const uint4*)(Wt + ((size_t)r * NBq + b) * 256 + o * 16);
      uint4 wa = wp[0], wb = wp[1];
      const float4* xp = (const float4*)(&xs[q][b * SIq]);
      float4 x0 = xp[0], x1 = xp[1], x2 = xp[2], x3 = xp[3];
      float a = x0.x*BF_LO(wa.x) + x0.y*BF_HI(wa.x) + x0.z*BF_LO(wa.y) + x0.w*BF_HI(wa.y)
              + x1.x*BF_LO(wa.z) + x1.y*BF_HI(wa.z) + x1.z*BF_LO(wa.w) + x1.w*BF_HI(wa.w)
              + x2.x*BF_LO(wb.x) + x2.y*BF_HI(wb.x) + x2.z*BF_LO(wb.y) + x2.w*BF_HI(wb.y)
              + x3.x*BF_LO(wb.z) + x3.y*BF_HI(wb.z) + x3.z*BF_LO(wb.w) + x3.w*BF_HI(wb.w);
      acc = fmaf(a, nv, acc);
    }
    __syncthreads();
  }
  agg[(size_t)n * Hdim + f] = acc;
}

// ---------------- GEMM: C[M,Nc] = A[M,128] @ B[128,Nc] (+addm)(+bias)(+addm2)(relu) ----------------
__global__ __launch_bounds__(256) void k_gemm(
    const float* __restrict__ A, const float* __restrict__ B, float* __restrict__ C,
    const float* __restrict__ addm, const float* __restrict__ bias,
    const float* __restrict__ addm2, int M, int Nc, int relu) {
  __shared__ float As[32][34];
  __shared__ float Bs[32][64];
  int t  = threadIdx.x;
  int tx = t & 15, ty = t >> 4;
  int bm = blockIdx.x * 32, bn = blockIdx.y * 64;
  int arow = t >> 3, akq = (t & 7) << 2;
  int br0 = t >> 4,         bc0 = (t & 15) << 2;
  int br1 = (t + 256) >> 4, bc1 = bc0;
  float acc[2][4] = {};
  for (int k0 = 0; k0 < Hdim; k0 += 32) {
    float4 av  = *(const float4*)(A + (size_t)(bm + arow) * Hdim + k0 + akq);
    float4 bv0 = *(const float4*)(B + (size_t)(k0 + br0) * Nc + bn + bc0);
    float4 bv1 = *(const float4*)(B + (size_t)(k0 + br1) * Nc + bn + bc1);
    __syncthreads();
    As[akq + 0][arow] = av.x; As[akq + 1][arow] = av.y;
    As[akq + 2][arow] = av.z; As[akq + 3][arow] = av.w;
    *(float4*)&Bs[br0][bc0] = bv0;
    *(float4*)&Bs[br1][bc1] = bv1;
    __syncthreads();
#pragma unroll
    for (int kk = 0; kk < 32; ++kk) {
      float2 a  = *(const float2*)&As[kk][ty << 1];
      float4 bb = *(const float4*)&Bs[kk][tx << 2];
      acc[0][0] += a.x * bb.x; acc[0][1] += a.x * bb.y;
      acc[0][2] += a.x * bb.z; acc[0][3] += a.x * bb.w;
      acc[1][0] += a.y * bb.x; acc[1][1] += a.y * bb.y;
      acc[1][2] += a.y * bb.z; acc[1][3] += a.y * bb.w;
    }
  }
  int col = bn + (tx << 2);
  float4 bvv = {0.f, 0.f, 0.f, 0.f};
  if (bias) bvv = *(const float4*)(bias + col);
#pragma unroll
  for (int r = 0; r < 2; ++r) {
    int row = bm + (ty << 1) + r;
    size_t off = (size_t)row * Nc + col;
    float4 v;
    v.x = acc[r][0] + bvv.x; v.y = acc[r][1] + bvv.y;
    v.z = acc[r][2] + bvv.z; v.w = acc[r][3] + bvv.w;
    if (addm)  { float4 m = *(const float4*)(addm + off);  v.x += m.x; v.y += m.y; v.z += m.z; v.w += m.w; }
    if (addm2) { float4 m = *(const float4*)(addm2 + off); v.x += m.x; v.y += m.y; v.z += m.z; v.w += m.w; }
    if (relu) {
      v.x = fmaxf(v.x, 0.f); v.y = fmaxf(v.y, 0.f);
      v.z = fmaxf(v.z, 0.f); v.w = fmaxf(v.w, 0.f);
    }
    *(float4*)(C + off) = v;
  }
}

// ---------------- fused zml GEMM + reparameterization ----------------
// z[:, col] = (h2@Wz)[:, col] + bz[col] + exp((h2@Wz)[:, col+128] + bz[col+128]) * eps[:, col]
// BM=32, 64 mean-cols + matching 64 ls-cols per block; grid (M/32, 2).
__global__ __launch_bounds__(256) void k_gemm_z(
    const float* __restrict__ A, const float* __restrict__ B,
    const float* __restrict__ bz, const float* __restrict__ eps,
    float* __restrict__ Z, int M) {
  __shared__ float As[32][34];
  __shared__ float Bm[32][64];
  __shared__ float Bl[32][64];
  int t  = threadIdx.x;
  int tx = t & 15, ty = t >> 4;
  int bm = blockIdx.x * 32, bn = blockIdx.y * 64;
  int arow = t >> 3, akq = (t & 7) << 2;
  int br0 = t >> 4,         bc0 = (t & 15) << 2;
  int br1 = (t + 256) >> 4;
  float am[2][4] = {}, al[2][4] = {};
  for (int k0 = 0; k0 < Hdim; k0 += 32) {
    float4 av  = *(const float4*)(A + (size_t)(bm + arow) * Hdim + k0 + akq);
    float4 bm0 = *(const float4*)(B + (size_t)(k0 + br0) * 256 + bn + bc0);
    float4 bm1 = *(const float4*)(B + (size_t)(k0 + br1) * 256 + bn + bc0);
    float4 bl0 = *(const float4*)(B + (size_t)(k0 + br0) * 256 + bn + 128 + bc0);
    float4 bl1 = *(const float4*)(B + (size_t)(k0 + br1) * 256 + bn + 128 + bc0);
    __syncthreads();
    As[akq + 0][arow] = av.x; As[akq + 1][arow] = av.y;
    As[akq + 2][arow] = av.z; As[akq + 3][arow] = av.w;
    *(float4*)&Bm[br0][bc0] = bm0;
    *(float4*)&Bm[br1][bc0] = bm1;
    *(float4*)&Bl[br0][bc0] = bl0;
    *(float4*)&Bl[br1][bc0] = bl1;
    __syncthreads();
#pragma unroll
    for (int kk = 0; kk < 32; ++kk) {
      float2 a  = *(const float2*)&As[kk][ty << 1];
      float4 bbm = *(const float4*)&Bm[kk][tx << 2];
      float4 bbl = *(const float4*)&Bl[kk][tx << 2];
      am[0][0] += a.x * bbm.x; am[0][1] += a.x * bbm.y;
      am[0][2] += a.x * bbm.z; am[0][3] += a.x * bbm.w;
      am[1][0] += a.y * bbm.x; am[1][1] += a.y * bbm.y;
      am[1][2] += a.y * bbm.z; am[1][3] += a.y * bbm.w;
      al[0][0] += a.x * bbl.x; al[0][1] += a.x * bbl.y;
      al[0][2] += a.x * bbl.z; al[0][3] += a.x * bbl.w;
      al[1][0] += a.y * bbl.x; al[1][1] += a.y * bbl.y;
      al[1][2] += a.y * bbl.z; al[1][3] += a.y * bbl.w;
    }
  }
  int col = bn + (tx << 2);
  float4 bzm = *(const float4*)(bz + col);
  float4 bzl = *(const float4*)(bz + 128 + col);
#pragma unroll
  for (int r = 0; r < 2; ++r) {
    int row = bm + (ty << 1) + r;
    size_t off = (size_t)row * Hdim + col;
    float4 ev = *(const float4*)(eps + off);
    float4 v;
    v.x = am[r][0] + bzm.x + expf(al[r][0] + bzl.x) * ev.x;
    v.y = am[r][1] + bzm.y + expf(al[r][1] + bzl.y) * ev.y;
    v.z = am[r][2] + bzm.z + expf(al[r][2] + bzl.z) * ev.z;
    v.w = am[r][3] + bzm.w + expf(al[r][3] + bzl.w) * ev.w;
    *(float4*)(Z + off) = v;
  }
}

// ---------------- G[128,128] += X^T @ Y  (split-K, 4x4/thread, no spill) ----------------
__global__ __launch_bounds__(256) void k_xty(const float* __restrict__ X,
                                             const float* __restrict__ Y,
                                             float* __restrict__ G, int N) {
  __shared__ float xs[8][64];
  __shared__ float ys[8][64];
  int t  = threadIdx.x;
  int tx = t & 15, ty = t >> 4;
  int qr = blockIdx.y >> 1, qc = blockIdx.y & 1;
  int KC = N / gridDim.x;
  int k0 = blockIdx.x * KC;
  int m  = t >> 7, li = t & 127;
  int lr = li >> 4, lc = (li & 15) << 2;
  const float* S = m ? Y : X;
  int coff = (m ? qc : qr) * 64;
  float acc[4][4] = {};
  for (int kb = 0; kb < KC; kb += 8) {
    float4 v = *(const float4*)(S + (size_t)(k0 + kb + lr) * Hdim + coff + lc);
    __syncthreads();
    if (m) *(float4*)&ys[lr][lc] = v; else *(float4*)&xs[lr][lc] = v;
    __syncthreads();
#pragma unroll
    for (int kk = 0; kk < 8; ++kk) {
      float4 xv = *(const float4*)&xs[kk][ty << 2];
      float4 yv = *(const float4*)&ys[kk][tx << 2];
      acc[0][0] += xv.x * yv.x; acc[0][1] += xv.x * yv.y; acc[0][2] += xv.x * yv.z; acc[0][3] += xv.x * yv.w;
      acc[1][0] += xv.y * yv.x; acc[1][1] += xv.y * yv.y; acc[1][2] += xv.y * yv.z; acc[1][3] += xv.y * yv.w;
      acc[2][0] += xv.z * yv.x; acc[2][1] += xv.z * yv.y; acc[2][2] += xv.z * yv.z; acc[2][3] += xv.z * yv.w;
      acc[3][0] += xv.w * yv.x; acc[3][1] += xv.w * yv.y; acc[3][2] += xv.w * yv.z; acc[3][3] += xv.w * yv.w;
    }
  }
  int grow = qr * 64 + (ty << 2);
  int gcol = qc * 64 + (tx << 2);
#pragma unroll
  for (int r = 0; r < 4; ++r)
#pragma unroll
    for (int c = 0; c < 4; ++c)
      atomicAdd(&G[(size_t)(grow + r) * Hdim + gcol + c], acc[r][c]);
}

extern "C" void kernel_launch(void* const* d_in, const int* in_sizes, int n_in,
                              void* d_out, int out_size, void* d_ws, size_t ws_size,
                              hipStream_t stream) {
  const int*   node_ids = (const int*)d_in[0];
  const int*   src      = (const int*)d_in[1];
  const int*   dst      = (const int*)d_in[2];
  const int*   et       = (const int*)d_in[3];
  const float* norm     = (const float*)d_in[4];
  const float* eps      = (const float*)d_in[5];
  const float* emb      = (const float*)d_in[6];
  const float* W0       = (const float*)d_in[7];
  const float* loop0    = (const float*)d_in[8];
  const float* b0       = (const float*)d_in[9];
  const float* W1       = (const float*)d_in[10];
  const float* loop1    = (const float*)d_in[11];
  const float* b1       = (const float*)d_in[12];
  const float* Wz       = (const float*)d_in[13];
  const float* bz       = (const float*)d_in[14];
  const float* Wi       = (const float*)d_in[15];
  const float* bi       = (const float*)d_in[16];
  const float* hbi      = (const float*)d_in[17];
  const float* Wo       = (const float*)d_in[18];
  const float* bo       = (const float*)d_in[19];
  const float* hbo      = (const float*)d_in[20];
  float* out = (float*)d_out;

  const int N  = in_sizes[0];   // 8192
  const int E  = in_sizes[1];   // 131072
  const int RB = in_sizes[7] / (SIq * SIq);   // NREL * NBq = 720

  char* ws = (char*)d_ws;
  const size_t MB = 1u << 20;
  const size_t KB = 1u << 10;
  float* X0   = (float*)(ws + 0 * MB);
  float* B1p  = (float*)(ws + 4 * MB);
  float* B2p  = (float*)(ws + 8 * MB);
  float* AGG  = (float*)(ws + 12 * MB);
  float* B3p  = (float*)(ws + 16 * MB);
  float* G    = (float*)(ws + 20 * MB);
  int*   offp = (int*)(ws + 20 * MB + 256 * KB);
  int*   curp = (int*)(ws + 20 * MB + 512 * KB);
  int*   cntp = (int*)(ws + 20 * MB + 768 * KB);
  int*   psrc = (int*)(ws + 21 * MB);
  int*   pet  = (int*)(ws + 21 * MB + 512 * KB);
  float* pnrm = (float*)(ws + 22 * MB);
  unsigned short* Wt0 = (unsigned short*)(ws + 22 * MB + 512 * KB);  // 368 KB
  unsigned short* Wt1 = (unsigned short*)(ws + 23 * MB);             // 368 KB

  dim3 blk(256);

  // ---- preprocessing: dst CSR permute + bf16 W (amortized over both layers) ----
  hipMemsetAsync(cntp, 0, (size_t)N * sizeof(int), stream);
  k_hist<<<dim3((E + 255) / 256), blk, 0, stream>>>(dst, cntp, E);
  k_scan<<<dim3(1), dim3(1024), 0, stream>>>(cntp, offp, curp, N, E);
  k_scatter<<<dim3((E + 255) / 256), blk, 0, stream>>>(src, dst, et, norm, curp,
                                                       psrc, pet, pnrm, E);
  k_wtb<<<dim3(RB), blk, 0, stream>>>(W0, Wt0);
  k_wtb<<<dim3(RB), blk, 0, stream>>>(W1, Wt1);

  // 1. x0
  k_gather<<<dim3((N * (Hdim / 4) + 255) / 256), blk, 0, stream>>>(emb, node_ids, X0, N);
  // 2. layer-0 edge aggregation (segment-reduce, bf16 W)
  k_edge4<<<dim3(N), dim3(128), 0, stream>>>(X0, Wt0, offp, psrc, pet, pnrm, AGG);
  // 3. h1 = relu(agg + b0 + x0@loop0)
  k_gemm<<<dim3(N / 32, Hdim / 64), blk, 0, stream>>>(X0, loop0, B1p, AGG, b0, nullptr, N, Hdim, 1);
  // 4. layer-1 edge aggregation
  k_edge4<<<dim3(N), dim3(128), 0, stream>>>(B1p, Wt1, offp, psrc, pet, pnrm, AGG);
  // 5. h2 = agg + b1 + h1@loop1
  k_gemm<<<dim3(N / 32, Hdim / 64), blk, 0, stream>>>(B1p, loop1, B2p, AGG, b1, nullptr, N, Hdim, 0);
  // 6+7. z = mean + exp(log_std)*eps, fused with zml GEMM -> B1p
  k_gemm_z<<<dim3(N / 32, 2), blk, 0, stream>>>(B2p, Wz, bz, eps, B1p, N);
  // 8. C1 = z@Wi + bi + x0 -> B3p
  k_gemm<<<dim3(N / 32, Hdim / 64), blk, 0, stream>>>(B1p, Wi, B3p, nullptr, bi, X0, N, Hdim, 0);
  // 9. G1 = z^T @ C1
  hipMemsetAsync(G, 0, (size_t)Hdim * Hdim * sizeof(float), stream);
  k_xty<<<dim3(32, 4), blk, 0, stream>>>(B1p, B3p, G, N);
  // 10. h3 = z@G1 + hbi -> B2p
  k_gemm<<<dim3(N / 32, Hdim / 64), blk, 0, stream>>>(B1p, G, B2p, nullptr, hbi, nullptr, N, Hdim, 0);
  // 11. C2 = h3@Wo + bo + x0 -> B3p
  k_gemm<<<dim3(N / 32, Hdim / 64), blk, 0, stream>>>(B2p, Wo, B3p, nullptr, bo, X0, N, Hdim, 0);
  // 12. G2 = h3^T @ C2
  hipMemsetAsync(G, 0, (size_t)Hdim * Hdim * sizeof(float), stream);
  k_xty<<<dim3(32, 4), blk, 0, stream>>>(B2p, B3p, G, N);
  // 13. out = h3@G2 + hbo
  k_gemm<<<dim3(N / 32, Hdim / 64), blk, 0, stream>>>(B2p, G, out, nullptr, hbo, nullptr, N, Hdim, 0);
}